// Round 1
// baseline (2551.219 us; speedup 1.0000x reference)
//
#include <hip/hip_runtime.h>
#include <cstdint>
#include <cstddef>

#define HIDN 256
#define NHEAD 8
#define HD 32
#define NSEQ 2048
#define TT 16                 // tokens per block (proj / epilogue)
#define SCALE 0.17677669529663687f   // 1/sqrt(32)

// ---------------------------------------------------------------------------
// Kernel 1: projections. Computes q,k (B,8,2048,32), v_all (B,8,2048,128)
// (v in dims 0..31, vec gathered per-head into dims 32..127), vec_dot and
// vec_norm (B*N,256).
// ---------------------------------------------------------------------------
__global__ __launch_bounds__(256) void proj_kernel(
    const float* __restrict__ x,
    const float* __restrict__ Wq, const float* __restrict__ bq,
    const float* __restrict__ Wk, const float* __restrict__ bk,
    const float* __restrict__ Wv, const float* __restrict__ bv,
    const float* __restrict__ Wvec,
    float* __restrict__ qo, float* __restrict__ ko, float* __restrict__ vall,
    float* __restrict__ doto, float* __restrict__ normo)
{
    __shared__ float xs[TT][HIDN];      // 16 KB
    __shared__ float vec[TT][3*HIDN];   // 48 KB
    const int tid = threadIdx.x;
    const int m0 = blockIdx.x * TT;

    // stage 16 tokens x 1024 floats (r=0 -> xs, r=1..3 -> vec)
    const float4* x4 = (const float4*)(x + (size_t)m0 * 1024);
    #pragma unroll
    for (int l = 0; l < 16; l++) {
        int i = tid + l * 256;
        int t = i >> 8;
        int c4 = i & 255;           // float4 index within token (256 = 1024 floats)
        float4 v = x4[i];
        if (c4 < 64) ((float4*)xs[t])[c4] = v;
        else         ((float4*)vec[t])[c4 - 64] = v;
    }
    __syncthreads();

    const int j = tid;              // output channel 0..255
    const int h = j >> 5, d = j & 31;

    // ---- QKV: thread j computes channel j for 16 tokens ----
    float aq[TT], ak[TT], av[TT];
    #pragma unroll
    for (int t = 0; t < TT; t++) { aq[t] = 0.f; ak[t] = 0.f; av[t] = 0.f; }
    const float4* Wq4 = (const float4*)Wq;
    const float4* Wk4 = (const float4*)Wk;
    const float4* Wv4 = (const float4*)Wv;
    for (int kk = 0; kk < 64; kk++) {
        float4 wq = Wq4[j * 64 + kk];
        float4 wk = Wk4[j * 64 + kk];
        float4 wv = Wv4[j * 64 + kk];
        #pragma unroll
        for (int t = 0; t < TT; t++) {
            float4 xv = ((const float4*)xs[t])[kk];
            aq[t] += xv.x * wq.x + xv.y * wq.y + xv.z * wq.z + xv.w * wq.w;
            ak[t] += xv.x * wk.x + xv.y * wk.y + xv.z * wk.z + xv.w * wk.w;
            av[t] += xv.x * wv.x + xv.y * wv.y + xv.z * wv.z + xv.w * wv.w;
        }
    }
    const float bqj = bq[j], bkj = bk[j], bvj = bv[j];
    #pragma unroll
    for (int t = 0; t < TT; t++) {
        int m = m0 + t;
        int b = m >> 11, n = m & 2047;
        size_t rbase = ((size_t)(b * NHEAD + h) * NSEQ + n);
        qo[rbase * HD + d] = aq[t] + bqj;
        ko[rbase * HD + d] = ak[t] + bkj;
        vall[rbase * 128 + d] = av[t] + bvj;
    }

    // ---- vec_proj -> vec_dot ----
    float dac[TT];
    #pragma unroll
    for (int t = 0; t < TT; t++) dac[t] = 0.f;
    const float4* Wvec4 = (const float4*)Wvec;
    for (int c = 0; c < 3; c++) {
        float a1[TT], a2[TT];
        #pragma unroll
        for (int t = 0; t < TT; t++) { a1[t] = 0.f; a2[t] = 0.f; }
        for (int kk = 0; kk < 64; kk++) {
            float4 w1 = Wvec4[j * 64 + kk];
            float4 w2 = Wvec4[(j + 256) * 64 + kk];
            #pragma unroll
            for (int t = 0; t < TT; t++) {
                float4 xv = ((const float4*)(vec[t] + c * HIDN))[kk];
                a1[t] += xv.x * w1.x + xv.y * w1.y + xv.z * w1.z + xv.w * w1.w;
                a2[t] += xv.x * w2.x + xv.y * w2.y + xv.z * w2.z + xv.w * w2.w;
            }
        }
        #pragma unroll
        for (int t = 0; t < TT; t++) dac[t] += a1[t] * a2[t];
    }
    #pragma unroll
    for (int t = 0; t < TT; t++) {
        int m = m0 + t;
        doto[(size_t)m * HIDN + j] = dac[t];
        float v0 = vec[t][j], v1 = vec[t][HIDN + j], v2 = vec[t][2 * HIDN + j];
        normo[(size_t)m * HIDN + j] = sqrtf(v0 * v0 + v1 * v1 + v2 * v2);
        int b = m >> 11, n = m & 2047;
        size_t rbase = ((size_t)(b * NHEAD + h) * NSEQ + n);
        vall[rbase * 128 + 32 + 0 * 32 + d] = vec[t][0 * HIDN + j];
        vall[rbase * 128 + 32 + 1 * 32 + d] = vec[t][1 * HIDN + j];
        vall[rbase * 128 + 32 + 2 * 32 + d] = vec[t][2 * HIDN + j];
    }
}

// ---------------------------------------------------------------------------
// Kernel 2: flash attention (fp32). One block per (b*8+h, q-tile of 64).
// ---------------------------------------------------------------------------
__global__ __launch_bounds__(256) void attn_kernel(
    const float* __restrict__ q, const float* __restrict__ k,
    const float* __restrict__ vall, float* __restrict__ oall)
{
    __shared__ float Qs[64 * 36];   // stride 36 floats: 16B-aligned rows, no b128 conflicts
    __shared__ float Ks[64 * 36];
    __shared__ float Ps[64 * 65];   // stride 65 breaks scalar-read bank aliasing
    __shared__ float mrow[64], lrow[64], arow[64];

    const int tid = threadIdx.x;
    const int bh = blockIdx.x >> 5;     // 0..31
    const int qt = blockIdx.x & 31;     // q tile
    const float* qbase = q + ((size_t)bh * NSEQ + qt * 64) * HD;
    const float* kbase = k + (size_t)bh * NSEQ * HD;
    const float* vbase = vall + (size_t)bh * NSEQ * 128;

    // load Q tile (scaled)
    #pragma unroll
    for (int l = 0; l < 2; l++) {
        int i = tid + l * 256;          // 512 float4
        int r = i >> 3, c4 = i & 7;
        float4 v = ((const float4*)qbase)[i];
        v.x *= SCALE; v.y *= SCALE; v.z *= SCALE; v.w *= SCALE;
        ((float4*)&Qs[r * 36])[c4] = v;
    }
    if (tid < 64) { mrow[tid] = -1e30f; lrow[tid] = 0.f; }
    __syncthreads();

    const int qr = tid >> 2;    // 0..63 query row
    const int q4 = tid & 3;     // d-group / k-group
    float4 out4[8];
    #pragma unroll
    for (int i = 0; i < 8; i++) out4[i] = float4{0.f, 0.f, 0.f, 0.f};

    for (int kt = 0; kt < 32; kt++) {
        // load K tile
        #pragma unroll
        for (int l = 0; l < 2; l++) {
            int i = tid + l * 256;
            int r = i >> 3, c4 = i & 7;
            ((float4*)&Ks[r * 36])[c4] = ((const float4*)(kbase + (size_t)kt * 64 * HD))[i];
        }
        __syncthreads();

        // scores: thread -> (qr, kc = q4 + 4*jj)
        float sacc[16];
        #pragma unroll
        for (int jj = 0; jj < 16; jj++) sacc[jj] = 0.f;
        #pragma unroll
        for (int dd = 0; dd < 8; dd++) {
            float4 qv = ((const float4*)&Qs[qr * 36])[dd];
            #pragma unroll
            for (int jj = 0; jj < 16; jj++) {
                float4 kv = ((const float4*)&Ks[(q4 + 4 * jj) * 36])[dd];
                sacc[jj] += qv.x * kv.x + qv.y * kv.y + qv.z * kv.z + qv.w * kv.w;
            }
        }
        #pragma unroll
        for (int jj = 0; jj < 16; jj++) Ps[qr * 65 + q4 + 4 * jj] = sacc[jj];
        __syncthreads();

        // online softmax, one thread per row
        if (tid < 64) {
            float mold = mrow[tid];
            float mx = mold;
            #pragma unroll 8
            for (int c = 0; c < 64; c++) mx = fmaxf(mx, Ps[tid * 65 + c]);
            float alpha = __expf(mold - mx);
            float s = 0.f;
            #pragma unroll 8
            for (int c = 0; c < 64; c++) {
                float p = __expf(Ps[tid * 65 + c] - mx);
                Ps[tid * 65 + c] = p;
                s += p;
            }
            mrow[tid] = mx;
            lrow[tid] = lrow[tid] * alpha + s;
            arow[tid] = alpha;
        }
        __syncthreads();

        // out update: thread accumulates (qr, d = q4*4 + 16*i + 0..3)
        float al = arow[qr];
        #pragma unroll
        for (int i = 0; i < 8; i++) {
            out4[i].x *= al; out4[i].y *= al; out4[i].z *= al; out4[i].w *= al;
        }
        const float* vt = vbase + (size_t)kt * 64 * 128;
        for (int kc = 0; kc < 64; kc++) {
            float p = Ps[qr * 65 + kc];
            const float4* vr = (const float4*)(vt + kc * 128);
            #pragma unroll
            for (int i = 0; i < 8; i++) {
                float4 vv = vr[q4 + 4 * i];
                out4[i].x += p * vv.x; out4[i].y += p * vv.y;
                out4[i].z += p * vv.z; out4[i].w += p * vv.w;
            }
        }
        __syncthreads();
    }

    float linv = 1.0f / lrow[qr];
    float4* orow = (float4*)(oall + ((size_t)bh * NSEQ + qt * 64 + qr) * 128);
    #pragma unroll
    for (int i = 0; i < 8; i++) {
        float4 v = out4[i];
        v.x *= linv; v.y *= linv; v.z *= linv; v.w *= linv;
        orow[q4 + 4 * i] = v;
    }
}

// ---------------------------------------------------------------------------
// Kernel 3: epilogue. gate GEMM (K=512) + Wo GEMM (K=256) + final combine.
// ---------------------------------------------------------------------------
__global__ __launch_bounds__(256) void epi_kernel(
    const float* __restrict__ x,
    const float* __restrict__ dotb, const float* __restrict__ normb,
    const float* __restrict__ oall,
    const float* __restrict__ Wg, const float* __restrict__ bg,
    const float* __restrict__ Wo, const float* __restrict__ bo,
    const float* __restrict__ alpha_dot, const float* __restrict__ alpha_norm,
    float* __restrict__ out)
{
    __shared__ float inv[TT][2 * HIDN];   // raw [dot | norm], 32 KB
    __shared__ float xo[TT][HIDN];        // x_out gathered, 16 KB
    const int tid = threadIdx.x;
    const int m0 = blockIdx.x * TT;
    const float ad = alpha_dot[0], an = alpha_norm[0];

    #pragma unroll
    for (int l = 0; l < 16; l++) {
        int i = tid + l * 256;
        int t = i >> 8, c = i & 255;
        int m = m0 + t;
        inv[t][c] = dotb[(size_t)m * HIDN + c];
        inv[t][HIDN + c] = normb[(size_t)m * HIDN + c];
        int b = m >> 11, n = m & 2047;
        xo[t][c] = oall[((size_t)(b * NHEAD + (c >> 5)) * NSEQ + n) * 128 + (c & 31)];
    }
    __syncthreads();

    const int j = tid;
    // gate: sigmoid([ad*dot, an*norm] @ Wg^T + bg)
    float ag[TT];
    #pragma unroll
    for (int t = 0; t < TT; t++) ag[t] = 0.f;
    const float4* Wg4 = (const float4*)Wg;
    for (int kk = 0; kk < 128; kk++) {
        float4 w = Wg4[j * 128 + kk];
        float sc = (kk < 64) ? ad : an;
        w.x *= sc; w.y *= sc; w.z *= sc; w.w *= sc;
        #pragma unroll
        for (int t = 0; t < TT; t++) {
            float4 iv = ((const float4*)inv[t])[kk];
            ag[t] += iv.x * w.x + iv.y * w.y + iv.z * w.z + iv.w * w.w;
        }
    }
    // o = x_out @ Wo^T + bo, rows j, j+256, j+512
    float a1[TT], a2[TT], a3[TT];
    #pragma unroll
    for (int t = 0; t < TT; t++) { a1[t] = 0.f; a2[t] = 0.f; a3[t] = 0.f; }
    const float4* Wo4 = (const float4*)Wo;
    for (int kk = 0; kk < 64; kk++) {
        float4 w1 = Wo4[j * 64 + kk];
        float4 w2 = Wo4[(j + 256) * 64 + kk];
        float4 w3 = Wo4[(j + 512) * 64 + kk];
        #pragma unroll
        for (int t = 0; t < TT; t++) {
            float4 xv = ((const float4*)xo[t])[kk];
            a1[t] += xv.x * w1.x + xv.y * w1.y + xv.z * w1.z + xv.w * w1.w;
            a2[t] += xv.x * w2.x + xv.y * w2.y + xv.z * w2.z + xv.w * w2.w;
            a3[t] += xv.x * w3.x + xv.y * w3.y + xv.z * w3.z + xv.w * w3.w;
        }
    }
    const float bgj = bg[j];
    const float bo1 = bo[j], bo2 = bo[256 + j], bo3 = bo[512 + j];
    const int h = j >> 5, d = j & 31;
    #pragma unroll
    for (int t = 0; t < TT; t++) {
        int m = m0 + t;
        int b = m >> 11, n = m & 2047;
        float dj = inv[t][j], nj = inv[t][HIDN + j];
        float o1 = a1[t] + bo1, o2 = a2[t] + bo2, o3 = a3[t] + bo3;
        float g = 1.f / (1.f + __expf(-(ag[t] + bgj)));
        size_t ob = (size_t)m * 1024;
        out[ob + j] = dj * o1 + nj * o2 + o3;
        size_t rbase = ((size_t)(b * NHEAD + h) * NSEQ + n) * 128;
        #pragma unroll
        for (int c = 0; c < 3; c++) {
            float va = oall[rbase + 32 + c * 32 + d];
            float vv = x[ob + (1 + c) * 256 + j];
            out[ob + (1 + c) * 256 + j] = g * va + vv;
        }
    }
}

// ---------------------------------------------------------------------------
extern "C" void kernel_launch(void* const* d_in, const int* in_sizes, int n_in,
                              void* d_out, int out_size, void* d_ws, size_t ws_size,
                              hipStream_t stream)
{
    const float* x    = (const float*)d_in[0];
    const float* Wq   = (const float*)d_in[1];
    const float* bq   = (const float*)d_in[2];
    const float* Wk   = (const float*)d_in[3];
    const float* bk   = (const float*)d_in[4];
    const float* Wv   = (const float*)d_in[5];
    const float* bv   = (const float*)d_in[6];
    const float* Wvec = (const float*)d_in[7];
    const float* Wo   = (const float*)d_in[8];
    const float* bo   = (const float*)d_in[9];
    const float* Wg   = (const float*)d_in[10];
    const float* bg   = (const float*)d_in[11];
    const float* adp  = (const float*)d_in[12];
    const float* anp  = (const float*)d_in[13];
    float* out = (float*)d_out;

    float* ws    = (float*)d_ws;
    float* qb    = ws;                  // 4*8*2048*32  = 2,097,152
    float* kb    = qb + 2097152;        // 2,097,152
    float* vallb = kb + 2097152;        // 4*8*2048*128 = 8,388,608
    float* dotb  = vallb + 8388608;     // 2,097,152
    float* normb = dotb + 2097152;      // 2,097,152
    float* oallb = normb + 2097152;     // 8,388,608
    // total = 25,165,824 floats = 96 MB

    proj_kernel<<<512, 256, 0, stream>>>(x, Wq, bq, Wk, bk, Wv, bv, Wvec,
                                         qb, kb, vallb, dotb, normb);
    attn_kernel<<<1024, 256, 0, stream>>>(qb, kb, vallb, oallb);
    epi_kernel<<<512, 256, 0, stream>>>(x, dotb, normb, oallb,
                                        Wg, bg, Wo, bo, adp, anp, out);
}

// Round 2
// 676.416 us; speedup vs baseline: 3.7717x; 3.7717x over previous
//
#include <hip/hip_runtime.h>
#include <cstdint>
#include <cstddef>

#define HIDN 256
#define NHEAD 8
#define HD 32
#define NSEQ 2048
#define TT 16
#define SCALE 0.17677669529663687f   // 1/sqrt(32)

typedef __attribute__((ext_vector_type(8))) short short8;
typedef __attribute__((ext_vector_type(4))) short short4v;
typedef __attribute__((ext_vector_type(4))) float f32x4;

static __device__ __forceinline__ short f2bf(float f) {
    union { float f; uint32_t u; } v; v.f = f;
    uint32_t r = (v.u + 0x7FFF + ((v.u >> 16) & 1)) >> 16;
    return (short)r;
}

// ---------------------------------------------------------------------------
// Kernel 1: projections -> bf16 Q (scaled), bf16 K, bf16 V^T (bh,128,2048),
// plus fp32 vec_dot and vec_norm (B*N,256).
// ---------------------------------------------------------------------------
__global__ __launch_bounds__(256) void proj_kernel(
    const float* __restrict__ x,
    const float* __restrict__ Wq, const float* __restrict__ bq,
    const float* __restrict__ Wk, const float* __restrict__ bk,
    const float* __restrict__ Wv, const float* __restrict__ bv,
    const float* __restrict__ Wvec,
    short* __restrict__ qbf, short* __restrict__ kbf, short* __restrict__ vtb,
    float* __restrict__ doto, float* __restrict__ normo)
{
    __shared__ float xs[TT][HIDN];      // 16 KB
    __shared__ float vec[TT][3*HIDN];   // 48 KB
    const int tid = threadIdx.x;
    const int m0 = blockIdx.x * TT;
    const int b  = m0 >> 11;
    const int n0 = m0 & 2047;

    const float4* x4 = (const float4*)(x + (size_t)m0 * 1024);
    #pragma unroll
    for (int l = 0; l < 16; l++) {
        int i = tid + l * 256;
        int t = i >> 8;
        int c4 = i & 255;
        float4 v = x4[i];
        if (c4 < 64) ((float4*)xs[t])[c4] = v;
        else         ((float4*)vec[t])[c4 - 64] = v;
    }
    __syncthreads();

    const int j = tid;
    const int h = j >> 5, d = j & 31;
    const int b8h = b * NHEAD + h;

    // ---- QKV ----
    float aq[TT], ak[TT], av[TT];
    #pragma unroll
    for (int t = 0; t < TT; t++) { aq[t] = 0.f; ak[t] = 0.f; av[t] = 0.f; }
    const float4* Wq4 = (const float4*)Wq;
    const float4* Wk4 = (const float4*)Wk;
    const float4* Wv4 = (const float4*)Wv;
    for (int kk = 0; kk < 64; kk++) {
        float4 wq = Wq4[j * 64 + kk];
        float4 wk = Wk4[j * 64 + kk];
        float4 wv = Wv4[j * 64 + kk];
        #pragma unroll
        for (int t = 0; t < TT; t++) {
            float4 xv = ((const float4*)xs[t])[kk];
            aq[t] += xv.x * wq.x + xv.y * wq.y + xv.z * wq.z + xv.w * wq.w;
            ak[t] += xv.x * wk.x + xv.y * wk.y + xv.z * wk.z + xv.w * wk.w;
            av[t] += xv.x * wv.x + xv.y * wv.y + xv.z * wv.z + xv.w * wv.w;
        }
    }
    const float bqj = bq[j], bkj = bk[j], bvj = bv[j];
    // q,k bf16 (attention layout (bh, n, 32))
    #pragma unroll
    for (int t = 0; t < TT; t++) {
        size_t rbase = ((size_t)b8h * NSEQ + n0 + t) * HD + d;
        qbf[rbase] = f2bf((aq[t] + bqj) * SCALE);
        kbf[rbase] = f2bf(ak[t] + bkj);
    }
    // V^T row d: 16 consecutive n -> two short8 stores
    {
        short8 s0, s1;
        #pragma unroll
        for (int t = 0; t < 8; t++)  s0[t] = f2bf(av[t] + bvj);
        #pragma unroll
        for (int t = 0; t < 8; t++)  s1[t] = f2bf(av[8 + t] + bvj);
        size_t vrow = ((size_t)b8h * 128 + d) * NSEQ + n0;
        *(short8*)(vtb + vrow) = s0;
        *(short8*)(vtb + vrow + 8) = s1;
    }
    // vec channels -> V^T rows 32 + c*32 + d
    #pragma unroll
    for (int c = 0; c < 3; c++) {
        short8 s0, s1;
        #pragma unroll
        for (int t = 0; t < 8; t++)  s0[t] = f2bf(vec[t][c * HIDN + j]);
        #pragma unroll
        for (int t = 0; t < 8; t++)  s1[t] = f2bf(vec[8 + t][c * HIDN + j]);
        size_t vrow = ((size_t)b8h * 128 + 32 + c * 32 + d) * NSEQ + n0;
        *(short8*)(vtb + vrow) = s0;
        *(short8*)(vtb + vrow + 8) = s1;
    }

    // ---- vec_proj -> vec_dot ----
    float dac[TT];
    #pragma unroll
    for (int t = 0; t < TT; t++) dac[t] = 0.f;
    const float4* Wvec4 = (const float4*)Wvec;
    for (int c = 0; c < 3; c++) {
        float a1[TT], a2[TT];
        #pragma unroll
        for (int t = 0; t < TT; t++) { a1[t] = 0.f; a2[t] = 0.f; }
        for (int kk = 0; kk < 64; kk++) {
            float4 w1 = Wvec4[j * 64 + kk];
            float4 w2 = Wvec4[(j + 256) * 64 + kk];
            #pragma unroll
            for (int t = 0; t < TT; t++) {
                float4 xv = ((const float4*)(vec[t] + c * HIDN))[kk];
                a1[t] += xv.x * w1.x + xv.y * w1.y + xv.z * w1.z + xv.w * w1.w;
                a2[t] += xv.x * w2.x + xv.y * w2.y + xv.z * w2.z + xv.w * w2.w;
            }
        }
        #pragma unroll
        for (int t = 0; t < TT; t++) dac[t] += a1[t] * a2[t];
    }
    #pragma unroll
    for (int t = 0; t < TT; t++) {
        int m = m0 + t;
        doto[(size_t)m * HIDN + j] = dac[t];
        float v0 = vec[t][j], v1 = vec[t][HIDN + j], v2 = vec[t][2 * HIDN + j];
        normo[(size_t)m * HIDN + j] = sqrtf(v0 * v0 + v1 * v1 + v2 * v2);
    }
}

// ---------------------------------------------------------------------------
// Kernel 2: MFMA flash attention. 512 blocks x 256 thr. Per block: 128 queries
// of one (b,h). Per wave: 32 queries (2 m-strips of 16). Barrier-free: P lives
// in a per-wave LDS buffer. S^T = K*Q^T so softmax is 2 shfl_xors.
// ---------------------------------------------------------------------------
__global__ __launch_bounds__(256) void attn_mfma(
    const short* __restrict__ qb, const short* __restrict__ kb,
    const short* __restrict__ vtb, float* __restrict__ oall)
{
    __shared__ short Pl[4][2][16 * 72];   // [wave][strip][m][72] = 18.4 KB

    const int tid  = threadIdx.x;
    const int wave = tid >> 6;
    const int lane = tid & 63;
    const int col  = lane & 15;
    const int quad = lane >> 4;

    const int bh = blockIdx.x >> 4;
    const int qt = blockIdx.x & 15;
    const int m0 = qt * 128 + wave * 32;

    const short* qbase = qb + (size_t)bh * NSEQ * HD;
    const short* kbase = kb + (size_t)bh * NSEQ * HD;
    const short* vbase = vtb + (size_t)bh * 128 * NSEQ;

    short8 qfrag[2];
    #pragma unroll
    for (int s = 0; s < 2; s++)
        qfrag[s] = *(const short8*)(qbase + (size_t)(m0 + s * 16 + col) * HD + quad * 8);

    f32x4 o[2][8];
    #pragma unroll
    for (int s = 0; s < 2; s++)
        #pragma unroll
        for (int dt = 0; dt < 8; dt++)
            o[s][dt] = (f32x4){0.f, 0.f, 0.f, 0.f};
    float mrun[2] = {-1e30f, -1e30f};
    float lrun[2] = {0.f, 0.f};

    for (int kt = 0; kt < 32; kt++) {
        const short* kt0 = kbase + (size_t)kt * 64 * HD;
        short8 kf[4];
        #pragma unroll
        for (int nt = 0; nt < 4; nt++)
            kf[nt] = *(const short8*)(kt0 + (nt * 16 + col) * HD + quad * 8);

        float alpha[2];
        #pragma unroll
        for (int s = 0; s < 2; s++) {
            f32x4 sc[4];
            #pragma unroll
            for (int nt = 0; nt < 4; nt++)
                sc[nt] = __builtin_amdgcn_mfma_f32_16x16x32_bf16(
                    kf[nt], qfrag[s], (f32x4){0.f, 0.f, 0.f, 0.f}, 0, 0, 0);
            // row max for query column (col = lane&15)
            float mx = -1e30f;
            #pragma unroll
            for (int nt = 0; nt < 4; nt++)
                #pragma unroll
                for (int r = 0; r < 4; r++) mx = fmaxf(mx, sc[nt][r]);
            mx = fmaxf(mx, __shfl_xor(mx, 16));
            mx = fmaxf(mx, __shfl_xor(mx, 32));
            float mnew = fmaxf(mrun[s], mx);
            alpha[s] = __expf(mrun[s] - mnew);
            mrun[s] = mnew;
            float rs = 0.f;
            short* pd = &Pl[wave][s][col * 72];
            #pragma unroll
            for (int nt = 0; nt < 4; nt++) {
                short4v pk;
                #pragma unroll
                for (int r = 0; r < 4; r++) {
                    float p = __expf(sc[nt][r] - mnew);
                    rs += p;
                    pk[r] = f2bf(p);
                }
                *(short4v*)(pd + nt * 16 + quad * 4) = pk;
            }
            rs += __shfl_xor(rs, 16);
            rs += __shfl_xor(rs, 32);
            lrun[s] = lrun[s] * alpha[s] + rs;
        }

        // rescale O by alpha (redistribute col-indexed alpha to row-indexed)
        #pragma unroll
        for (int s = 0; s < 2; s++) {
            float a0 = __shfl(alpha[s], quad * 4 + 0);
            float a1 = __shfl(alpha[s], quad * 4 + 1);
            float a2 = __shfl(alpha[s], quad * 4 + 2);
            float a3 = __shfl(alpha[s], quad * 4 + 3);
            #pragma unroll
            for (int dt = 0; dt < 8; dt++) {
                o[s][dt][0] *= a0; o[s][dt][1] *= a1;
                o[s][dt][2] *= a2; o[s][dt][3] *= a3;
            }
        }

        // PV: O[m][d] += P[m][n] * V[n][d]
        const short* vt0 = vbase + kt * 64;
        #pragma unroll
        for (int c = 0; c < 2; c++) {
            short8 pa[2];
            #pragma unroll
            for (int s = 0; s < 2; s++)
                pa[s] = *(const short8*)(&Pl[wave][s][col * 72 + c * 32 + quad * 8]);
            #pragma unroll
            for (int dt = 0; dt < 8; dt++) {
                short8 vf = *(const short8*)(vt0 + (size_t)(dt * 16 + col) * NSEQ + c * 32 + quad * 8);
                #pragma unroll
                for (int s = 0; s < 2; s++)
                    o[s][dt] = __builtin_amdgcn_mfma_f32_16x16x32_bf16(pa[s], vf, o[s][dt], 0, 0, 0);
            }
        }
    }

    #pragma unroll
    for (int s = 0; s < 2; s++) {
        float linv = 1.0f / lrun[s];
        float i0 = __shfl(linv, quad * 4 + 0);
        float i1 = __shfl(linv, quad * 4 + 1);
        float i2 = __shfl(linv, quad * 4 + 2);
        float i3 = __shfl(linv, quad * 4 + 3);
        float* ob = oall + ((size_t)bh * NSEQ + m0 + s * 16) * 128;
        #pragma unroll
        for (int dt = 0; dt < 8; dt++) {
            ob[(quad * 4 + 0) * 128 + dt * 16 + col] = o[s][dt][0] * i0;
            ob[(quad * 4 + 1) * 128 + dt * 16 + col] = o[s][dt][1] * i1;
            ob[(quad * 4 + 2) * 128 + dt * 16 + col] = o[s][dt][2] * i2;
            ob[(quad * 4 + 3) * 128 + dt * 16 + col] = o[s][dt][3] * i3;
        }
    }
}

// ---------------------------------------------------------------------------
// Kernel 3: epilogue. gate GEMM (K=512) + Wo GEMM (K=256) + final combine.
// ---------------------------------------------------------------------------
__global__ __launch_bounds__(256) void epi_kernel(
    const float* __restrict__ x,
    const float* __restrict__ dotb, const float* __restrict__ normb,
    const float* __restrict__ oall,
    const float* __restrict__ Wg, const float* __restrict__ bg,
    const float* __restrict__ Wo, const float* __restrict__ bo,
    const float* __restrict__ alpha_dot, const float* __restrict__ alpha_norm,
    float* __restrict__ out)
{
    __shared__ float inv[TT][2 * HIDN];
    __shared__ float xo[TT][HIDN];
    const int tid = threadIdx.x;
    const int m0 = blockIdx.x * TT;
    const float ad = alpha_dot[0], an = alpha_norm[0];

    #pragma unroll
    for (int l = 0; l < 16; l++) {
        int i = tid + l * 256;
        int t = i >> 8, c = i & 255;
        int m = m0 + t;
        inv[t][c] = dotb[(size_t)m * HIDN + c];
        inv[t][HIDN + c] = normb[(size_t)m * HIDN + c];
        int b = m >> 11, n = m & 2047;
        xo[t][c] = oall[((size_t)(b * NHEAD + (c >> 5)) * NSEQ + n) * 128 + (c & 31)];
    }
    __syncthreads();

    const int j = tid;
    float ag[TT];
    #pragma unroll
    for (int t = 0; t < TT; t++) ag[t] = 0.f;
    const float4* Wg4 = (const float4*)Wg;
    for (int kk = 0; kk < 128; kk++) {
        float4 w = Wg4[j * 128 + kk];
        float sc = (kk < 64) ? ad : an;
        w.x *= sc; w.y *= sc; w.z *= sc; w.w *= sc;
        #pragma unroll
        for (int t = 0; t < TT; t++) {
            float4 iv = ((const float4*)inv[t])[kk];
            ag[t] += iv.x * w.x + iv.y * w.y + iv.z * w.z + iv.w * w.w;
        }
    }
    float a1[TT], a2[TT], a3[TT];
    #pragma unroll
    for (int t = 0; t < TT; t++) { a1[t] = 0.f; a2[t] = 0.f; a3[t] = 0.f; }
    const float4* Wo4 = (const float4*)Wo;
    for (int kk = 0; kk < 64; kk++) {
        float4 w1 = Wo4[j * 64 + kk];
        float4 w2 = Wo4[(j + 256) * 64 + kk];
        float4 w3 = Wo4[(j + 512) * 64 + kk];
        #pragma unroll
        for (int t = 0; t < TT; t++) {
            float4 xv = ((const float4*)xo[t])[kk];
            a1[t] += xv.x * w1.x + xv.y * w1.y + xv.z * w1.z + xv.w * w1.w;
            a2[t] += xv.x * w2.x + xv.y * w2.y + xv.z * w2.z + xv.w * w2.w;
            a3[t] += xv.x * w3.x + xv.y * w3.y + xv.z * w3.z + xv.w * w3.w;
        }
    }
    const float bgj = bg[j];
    const float bo1 = bo[j], bo2 = bo[256 + j], bo3 = bo[512 + j];
    const int h = j >> 5, d = j & 31;
    #pragma unroll
    for (int t = 0; t < TT; t++) {
        int m = m0 + t;
        int b = m >> 11, n = m & 2047;
        float dj = inv[t][j], nj = inv[t][HIDN + j];
        float o1 = a1[t] + bo1, o2 = a2[t] + bo2, o3 = a3[t] + bo3;
        float g = 1.f / (1.f + __expf(-(ag[t] + bgj)));
        size_t ob = (size_t)m * 1024;
        out[ob + j] = dj * o1 + nj * o2 + o3;
        size_t rbase = ((size_t)(b * NHEAD + h) * NSEQ + n) * 128;
        #pragma unroll
        for (int c = 0; c < 3; c++) {
            float va = oall[rbase + 32 + c * 32 + d];
            float vv = x[ob + (1 + c) * 256 + j];
            out[ob + (1 + c) * 256 + j] = g * va + vv;
        }
    }
}

// ---------------------------------------------------------------------------
extern "C" void kernel_launch(void* const* d_in, const int* in_sizes, int n_in,
                              void* d_out, int out_size, void* d_ws, size_t ws_size,
                              hipStream_t stream)
{
    const float* x    = (const float*)d_in[0];
    const float* Wq   = (const float*)d_in[1];
    const float* bq   = (const float*)d_in[2];
    const float* Wk   = (const float*)d_in[3];
    const float* bk   = (const float*)d_in[4];
    const float* Wv   = (const float*)d_in[5];
    const float* bv   = (const float*)d_in[6];
    const float* Wvec = (const float*)d_in[7];
    const float* Wo   = (const float*)d_in[8];
    const float* bo   = (const float*)d_in[9];
    const float* Wg   = (const float*)d_in[10];
    const float* bg   = (const float*)d_in[11];
    const float* adp  = (const float*)d_in[12];
    const float* anp  = (const float*)d_in[13];
    float* out = (float*)d_out;

    float* ws    = (float*)d_ws;
    short* qbf   = (short*)ws;                       // 2,097,152 bf16 = 1,048,576 f
    short* kbf   = (short*)(ws + 1048576);           // 1,048,576 f
    short* vtb   = (short*)(ws + 2097152);           // 8,388,608 bf16 = 4,194,304 f
    float* dotb  = ws + 6291456;                     // 2,097,152 f
    float* normb = ws + 8388608;                     // 2,097,152 f
    float* oallb = ws + 10485760;                    // 8,388,608 f
    // total = 18,874,368 floats = 75.5 MB

    proj_kernel<<<512, 256, 0, stream>>>(x, Wq, bq, Wk, bk, Wv, bv, Wvec,
                                         qbf, kbf, vtb, dotb, normb);
    attn_mfma<<<512, 256, 0, stream>>>(qbf, kbf, vtb, oallb);
    epi_kernel<<<512, 256, 0, stream>>>(x, dotb, normb, oallb,
                                        Wg, bg, Wo, bo, adp, anp, out);
}

// Round 3
// 414.959 us; speedup vs baseline: 6.1481x; 1.6301x over previous
//
#include <hip/hip_runtime.h>
#include <cstdint>
#include <cstddef>

#define HIDN 256
#define NHEAD 8
#define HD 32
#define NSEQ 2048
#define QS (0.17677669529663687f * 1.4426950408889634f)   // 1/sqrt(32) * log2(e)

typedef __attribute__((ext_vector_type(8))) short short8;
typedef __attribute__((ext_vector_type(4))) short short4v;
typedef __attribute__((ext_vector_type(4))) float f32x4;

static __device__ __forceinline__ short f2bf(float f) {
    union { float f; uint32_t u; } v; v.f = f;
    uint32_t r = (v.u + 0x7FFF + ((v.u >> 16) & 1)) >> 16;
    return (short)r;
}

// ---------------------------------------------------------------------------
// Kernel 0: convert weights to bf16. Wq gets QS = SCALE*log2e folded in.
// Wqkvb rows: [0,256)=q*QS, [256,512)=k, [512,768)=v. Wvecb = Wvec (512x256).
// ---------------------------------------------------------------------------
__global__ __launch_bounds__(256) void wcvt_kernel(
    const float* __restrict__ Wq, const float* __restrict__ Wk,
    const float* __restrict__ Wv, const float* __restrict__ Wvec,
    const float* __restrict__ bq, const float* __restrict__ bk,
    const float* __restrict__ bv,
    short* __restrict__ Wqkvb, short* __restrict__ Wvecb, float* __restrict__ bqkvs)
{
    int idx = blockIdx.x * 256 + threadIdx.x;   // grid 1280 -> 327,680
    if (idx < 65536)       Wqkvb[idx] = f2bf(Wq[idx] * QS);
    else if (idx < 131072) Wqkvb[idx] = f2bf(Wk[idx - 65536]);
    else if (idx < 196608) Wqkvb[idx] = f2bf(Wv[idx - 131072]);
    else                   Wvecb[idx - 196608] = f2bf(Wvec[idx - 196608]);
    if (idx < 256)         bqkvs[idx] = bq[idx] * QS;
    else if (idx < 512)    bqkvs[idx] = bk[idx - 256];
    else if (idx < 768)    bqkvs[idx] = bv[idx - 512];
}

// ---------------------------------------------------------------------------
// Kernel 1: QKV via MFMA. grid (256 token-tiles of 32, 3: q/k/v). Block 256.
// Wave: 2 m-tiles x 4 n-tiles (32 tok x 64 ch). v goes transposed to vtb.
// ---------------------------------------------------------------------------
__global__ __launch_bounds__(256) void qkv_kernel(
    const float* __restrict__ x, const short* __restrict__ Wqkvb,
    const float* __restrict__ bqkvs,
    short* __restrict__ qbf, short* __restrict__ kbf, short* __restrict__ vtb)
{
    __shared__ short xs[32 * 264];     // 16.5 KB, padded (+8) rows
    __shared__ short vtmp[256 * 34];   // 17 KB transpose buffer (y==2)
    const int tid = threadIdx.x;
    const int m0 = blockIdx.x * 32;
    const int y  = blockIdx.y;
    const int b  = m0 >> 11;
    const int n0 = m0 & 2047;

    // stage x_scalar 32x256 -> bf16 LDS
    #pragma unroll
    for (int l = 0; l < 8; l++) {
        int i = l * 256 + tid;          // 2048 float4
        int t = i >> 6, j4 = i & 63;
        float4 v = *(const float4*)(x + (size_t)(m0 + t) * 1024 + j4 * 4);
        short4v s = { f2bf(v.x), f2bf(v.y), f2bf(v.z), f2bf(v.w) };
        *(short4v*)&xs[t * 264 + j4 * 4] = s;
    }
    __syncthreads();

    const int wave = tid >> 6, lane = tid & 63;
    const int col = lane & 15, quad = lane >> 4;

    f32x4 acc[2][4];
    #pragma unroll
    for (int mt = 0; mt < 2; mt++)
        #pragma unroll
        for (int nt = 0; nt < 4; nt++) acc[mt][nt] = (f32x4){0.f,0.f,0.f,0.f};

    const short* Wb = Wqkvb + (size_t)(y * 256 + wave * 64) * 256;
    #pragma unroll
    for (int kk = 0; kk < 8; kk++) {
        short8 xf[2];
        #pragma unroll
        for (int mt = 0; mt < 2; mt++)
            xf[mt] = *(const short8*)&xs[(mt * 16 + col) * 264 + kk * 32 + quad * 8];
        #pragma unroll
        for (int nt = 0; nt < 4; nt++) {
            short8 wf = *(const short8*)(Wb + (size_t)(nt * 16 + col) * 256 + kk * 32 + quad * 8);
            #pragma unroll
            for (int mt = 0; mt < 2; mt++)
                acc[mt][nt] = __builtin_amdgcn_mfma_f32_16x16x32_bf16(wf, xf[mt], acc[mt][nt], 0, 0, 0);
        }
    }

    if (y < 2) {
        short* dst = (y == 0) ? qbf : kbf;
        #pragma unroll
        for (int nt = 0; nt < 4; nt++) {
            int ch = wave * 64 + nt * 16 + quad * 4;
            float4 bi = *(const float4*)&bqkvs[y * 256 + ch];
            int h = ch >> 5, d = ch & 31;
            #pragma unroll
            for (int mt = 0; mt < 2; mt++) {
                int n = n0 + mt * 16 + col;
                short4v s = { f2bf(acc[mt][nt][0] + bi.x), f2bf(acc[mt][nt][1] + bi.y),
                              f2bf(acc[mt][nt][2] + bi.z), f2bf(acc[mt][nt][3] + bi.w) };
                *(short4v*)(dst + ((size_t)(b * 8 + h) * 2048 + n) * 32 + d) = s;
            }
        }
    } else {
        // v: write C into LDS transpose buffer, then vectorized stores
        #pragma unroll
        for (int nt = 0; nt < 4; nt++) {
            int ch = wave * 64 + nt * 16 + quad * 4;
            float4 bi = *(const float4*)&bqkvs[512 + ch];
            #pragma unroll
            for (int mt = 0; mt < 2; mt++) {
                int tok = mt * 16 + col;
                vtmp[(ch + 0) * 34 + tok] = f2bf(acc[mt][nt][0] + bi.x);
                vtmp[(ch + 1) * 34 + tok] = f2bf(acc[mt][nt][1] + bi.y);
                vtmp[(ch + 2) * 34 + tok] = f2bf(acc[mt][nt][2] + bi.z);
                vtmp[(ch + 3) * 34 + tok] = f2bf(acc[mt][nt][3] + bi.w);
            }
        }
        __syncthreads();
        int ch = tid;                   // 256 rows
        short s[32];
        #pragma unroll
        for (int t = 0; t < 32; t++) s[t] = vtmp[ch * 34 + t];
        size_t row = ((size_t)(b * 8 + (ch >> 5)) * 128 + (ch & 31)) * 2048 + n0;
        #pragma unroll
        for (int g = 0; g < 4; g++)
            *(short8*)(vtb + row + g * 8) = *(short8*)&s[g * 8];
    }
}

// ---------------------------------------------------------------------------
// Kernel 2: vec_dot via MFMA. grid 512 (16-token tiles), block 512 (8 waves,
// each 32 j-channels). dot[m][j] = sum_c S1[c][m][j]*S2[c][m][j].
// ---------------------------------------------------------------------------
__global__ __launch_bounds__(512) void vdot_kernel(
    const float* __restrict__ x, const short* __restrict__ Wvecb,
    float* __restrict__ dotb)
{
    __shared__ short vb[3 * 16 * 264];  // 25.3 KB
    const int tid = threadIdx.x;
    const int m0 = blockIdx.x * 16;

    #pragma unroll
    for (int p = 0; p < 6; p++) {
        int f4 = p * 512 + tid;          // 3072 float4
        int t = f4 / 192;
        int rem = f4 - t * 192;
        int c = rem >> 6, j4 = rem & 63;
        float4 v = *(const float4*)(x + (size_t)(m0 + t) * 1024 + 256 + c * 256 + j4 * 4);
        short4v s = { f2bf(v.x), f2bf(v.y), f2bf(v.z), f2bf(v.w) };
        *(short4v*)&vb[(c * 16 + t) * 264 + j4 * 4] = s;
    }
    __syncthreads();

    const int wave = tid >> 6, lane = tid & 63;
    const int col = lane & 15, quad = lane >> 4;
    const int j0 = wave * 32;

    f32x4 dac[2] = {(f32x4){0.f,0.f,0.f,0.f}, (f32x4){0.f,0.f,0.f,0.f}};
    #pragma unroll
    for (int c = 0; c < 3; c++) {
        f32x4 d1[2] = {(f32x4){0.f,0.f,0.f,0.f}, (f32x4){0.f,0.f,0.f,0.f}};
        f32x4 d2[2] = {(f32x4){0.f,0.f,0.f,0.f}, (f32x4){0.f,0.f,0.f,0.f}};
        #pragma unroll
        for (int kk = 0; kk < 8; kk++) {
            short8 xf = *(const short8*)&vb[(c * 16 + col) * 264 + kk * 32 + quad * 8];
            #pragma unroll
            for (int nt = 0; nt < 2; nt++) {
                short8 w1 = *(const short8*)&Wvecb[(size_t)(j0 + nt * 16 + col) * 256 + kk * 32 + quad * 8];
                short8 w2 = *(const short8*)&Wvecb[(size_t)(256 + j0 + nt * 16 + col) * 256 + kk * 32 + quad * 8];
                d1[nt] = __builtin_amdgcn_mfma_f32_16x16x32_bf16(w1, xf, d1[nt], 0, 0, 0);
                d2[nt] = __builtin_amdgcn_mfma_f32_16x16x32_bf16(w2, xf, d2[nt], 0, 0, 0);
            }
        }
        #pragma unroll
        for (int nt = 0; nt < 2; nt++) dac[nt] += d1[nt] * d2[nt];
    }
    #pragma unroll
    for (int nt = 0; nt < 2; nt++) {
        float4 o = { dac[nt][0], dac[nt][1], dac[nt][2], dac[nt][3] };
        *(float4*)&dotb[(size_t)(m0 + col) * 256 + j0 + nt * 16 + quad * 4] = o;
    }
}

// ---------------------------------------------------------------------------
// Kernel 3: elementwise — vec_norm + bf16 V^T rows 32..127. No LDS.
// ---------------------------------------------------------------------------
__global__ __launch_bounds__(256) void vecel_kernel(
    const float* __restrict__ x, float* __restrict__ normb, short* __restrict__ vtb)
{
    const int j = threadIdx.x;
    const int m0 = blockIdx.x * 16;
    const int b = m0 >> 11, n0 = m0 & 2047;
    const int h = j >> 5, d = j & 31;
    float vv[3][16];
    #pragma unroll
    for (int t = 0; t < 16; t++) {
        const float* xr = x + (size_t)(m0 + t) * 1024 + 256;
        float v0 = xr[j], v1 = xr[256 + j], v2 = xr[512 + j];
        vv[0][t] = v0; vv[1][t] = v1; vv[2][t] = v2;
        normb[(size_t)(m0 + t) * 256 + j] = sqrtf(v0 * v0 + v1 * v1 + v2 * v2);
    }
    #pragma unroll
    for (int c = 0; c < 3; c++) {
        short8 s0, s1;
        #pragma unroll
        for (int t = 0; t < 8; t++) { s0[t] = f2bf(vv[c][t]); s1[t] = f2bf(vv[c][8 + t]); }
        size_t row = ((size_t)(b * 8 + h) * 128 + 32 + c * 32 + d) * 2048 + n0;
        *(short8*)(vtb + row) = s0;
        *(short8*)(vtb + row + 8) = s1;
    }
}

// ---------------------------------------------------------------------------
// Kernel 4: MFMA flash attention v3. Grid 512 (bh x 16 q-tiles of 128).
// Block 256 (4 waves x 32 q). K/V staged in padded LDS. O is query-column
// indexed (PV = mfma(vf, pa)) so alpha/linv need no shuffles. exp2 domain.
// ---------------------------------------------------------------------------
__global__ __launch_bounds__(256) void attn_kernel(
    const short* __restrict__ qb, const short* __restrict__ kb,
    const short* __restrict__ vtb, float* __restrict__ oall)
{
    __shared__ short Ks[64 * 36];        // 4.6 KB
    __shared__ short Vs[128 * 68];       // 17.4 KB
    __shared__ short Pl[4][2][16 * 72];  // 18.4 KB
    const int tid = threadIdx.x;
    const int wave = tid >> 6, lane = tid & 63;
    const int col = lane & 15, quad = lane >> 4;
    const int bh = blockIdx.x >> 4, qt = blockIdx.x & 15;
    const int m0 = qt * 128 + wave * 32;

    const short* qbase = qb + (size_t)bh * NSEQ * HD;
    const short* kbase = kb + (size_t)bh * NSEQ * HD;
    const short* vbase = vtb + (size_t)bh * 128 * NSEQ;

    short8 qfrag[2];
    #pragma unroll
    for (int s = 0; s < 2; s++)
        qfrag[s] = *(const short8*)(qbase + (size_t)(m0 + s * 16 + col) * 32 + quad * 8);

    f32x4 o[2][8];
    #pragma unroll
    for (int s = 0; s < 2; s++)
        #pragma unroll
        for (int dt = 0; dt < 8; dt++) o[s][dt] = (f32x4){0.f,0.f,0.f,0.f};
    float mrun[2] = {-1e30f, -1e30f};
    float lrun[2] = {0.f, 0.f};

    for (int kt = 0; kt < 32; kt++) {
        __syncthreads();
        {   // stage K tile (64x32)
            int r = tid >> 2, seg = tid & 3;
            *(short8*)&Ks[r * 36 + seg * 8] =
                *(const short8*)(kbase + (size_t)(kt * 64 + r) * 32 + seg * 8);
        }
        #pragma unroll
        for (int p = 0; p < 4; p++) {   // stage V tile (128x64)
            int i = p * 256 + tid;
            int r = i >> 3, seg = i & 7;
            *(short8*)&Vs[r * 68 + seg * 8] =
                *(const short8*)(vbase + (size_t)r * NSEQ + kt * 64 + seg * 8);
        }
        __syncthreads();

        short8 kf[4];
        #pragma unroll
        for (int nt = 0; nt < 4; nt++)
            kf[nt] = *(const short8*)&Ks[(nt * 16 + col) * 36 + quad * 8];

        float alpha[2];
        #pragma unroll
        for (int s = 0; s < 2; s++) {
            f32x4 sc[4];
            #pragma unroll
            for (int nt = 0; nt < 4; nt++)
                sc[nt] = __builtin_amdgcn_mfma_f32_16x16x32_bf16(
                    kf[nt], qfrag[s], (f32x4){0.f,0.f,0.f,0.f}, 0, 0, 0);
            float mx = -1e30f;
            #pragma unroll
            for (int nt = 0; nt < 4; nt++)
                #pragma unroll
                for (int r = 0; r < 4; r++) mx = fmaxf(mx, sc[nt][r]);
            mx = fmaxf(mx, __shfl_xor(mx, 16));
            mx = fmaxf(mx, __shfl_xor(mx, 32));
            float mnew = fmaxf(mrun[s], mx);
            alpha[s] = exp2f(mrun[s] - mnew);
            mrun[s] = mnew;
            float rs = 0.f;
            short* pd = &Pl[wave][s][col * 72];
            #pragma unroll
            for (int nt = 0; nt < 4; nt++) {
                short4v pk;
                #pragma unroll
                for (int r = 0; r < 4; r++) {
                    float p = exp2f(sc[nt][r] - mnew);
                    rs += p;
                    pk[r] = f2bf(p);
                }
                *(short4v*)(pd + nt * 16 + quad * 4) = pk;
            }
            rs += __shfl_xor(rs, 16);
            rs += __shfl_xor(rs, 32);
            lrun[s] = lrun[s] * alpha[s] + rs;
        }

        #pragma unroll
        for (int s = 0; s < 2; s++)
            #pragma unroll
            for (int dt = 0; dt < 8; dt++) o[s][dt] *= alpha[s];

        #pragma unroll
        for (int c = 0; c < 2; c++) {
            short8 pa[2];
            #pragma unroll
            for (int s = 0; s < 2; s++)
                pa[s] = *(const short8*)&Pl[wave][s][col * 72 + c * 32 + quad * 8];
            #pragma unroll
            for (int dt = 0; dt < 8; dt++) {
                short8 vf = *(const short8*)&Vs[(dt * 16 + col) * 68 + c * 32 + quad * 8];
                #pragma unroll
                for (int s = 0; s < 2; s++)
                    o[s][dt] = __builtin_amdgcn_mfma_f32_16x16x32_bf16(vf, pa[s], o[s][dt], 0, 0, 0);
            }
        }
    }

    #pragma unroll
    for (int s = 0; s < 2; s++) {
        float linv = 1.0f / lrun[s];
        float* ob = oall + ((size_t)bh * NSEQ + m0 + s * 16 + col) * 128;
        #pragma unroll
        for (int dt = 0; dt < 8; dt++) {
            float4 v = { o[s][dt][0] * linv, o[s][dt][1] * linv,
                         o[s][dt][2] * linv, o[s][dt][3] * linv };
            *(float4*)(ob + dt * 16 + quad * 4) = v;
        }
    }
}

// ---------------------------------------------------------------------------
// Kernel 5: epilogue (unchanged): gate GEMM + Wo GEMM + final combine.
// ---------------------------------------------------------------------------
#define TT 16
__global__ __launch_bounds__(256) void epi_kernel(
    const float* __restrict__ x,
    const float* __restrict__ dotb, const float* __restrict__ normb,
    const float* __restrict__ oall,
    const float* __restrict__ Wg, const float* __restrict__ bg,
    const float* __restrict__ Wo, const float* __restrict__ bo,
    const float* __restrict__ alpha_dot, const float* __restrict__ alpha_norm,
    float* __restrict__ out)
{
    __shared__ float inv[TT][2 * HIDN];
    __shared__ float xo[TT][HIDN];
    const int tid = threadIdx.x;
    const int m0 = blockIdx.x * TT;
    const float ad = alpha_dot[0], an = alpha_norm[0];

    #pragma unroll
    for (int l = 0; l < 16; l++) {
        int i = tid + l * 256;
        int t = i >> 8, c = i & 255;
        int m = m0 + t;
        inv[t][c] = dotb[(size_t)m * HIDN + c];
        inv[t][HIDN + c] = normb[(size_t)m * HIDN + c];
        int b = m >> 11, n = m & 2047;
        xo[t][c] = oall[((size_t)(b * NHEAD + (c >> 5)) * NSEQ + n) * 128 + (c & 31)];
    }
    __syncthreads();

    const int j = tid;
    float ag[TT];
    #pragma unroll
    for (int t = 0; t < TT; t++) ag[t] = 0.f;
    const float4* Wg4 = (const float4*)Wg;
    for (int kk = 0; kk < 128; kk++) {
        float4 w = Wg4[j * 128 + kk];
        float sc = (kk < 64) ? ad : an;
        w.x *= sc; w.y *= sc; w.z *= sc; w.w *= sc;
        #pragma unroll
        for (int t = 0; t < TT; t++) {
            float4 iv = ((const float4*)inv[t])[kk];
            ag[t] += iv.x * w.x + iv.y * w.y + iv.z * w.z + iv.w * w.w;
        }
    }
    float a1[TT], a2[TT], a3[TT];
    #pragma unroll
    for (int t = 0; t < TT; t++) { a1[t] = 0.f; a2[t] = 0.f; a3[t] = 0.f; }
    const float4* Wo4 = (const float4*)Wo;
    for (int kk = 0; kk < 64; kk++) {
        float4 w1 = Wo4[j * 64 + kk];
        float4 w2 = Wo4[(j + 256) * 64 + kk];
        float4 w3 = Wo4[(j + 512) * 64 + kk];
        #pragma unroll
        for (int t = 0; t < TT; t++) {
            float4 xv = ((const float4*)xo[t])[kk];
            a1[t] += xv.x * w1.x + xv.y * w1.y + xv.z * w1.z + xv.w * w1.w;
            a2[t] += xv.x * w2.x + xv.y * w2.y + xv.z * w2.z + xv.w * w2.w;
            a3[t] += xv.x * w3.x + xv.y * w3.y + xv.z * w3.z + xv.w * w3.w;
        }
    }
    const float bgj = bg[j];
    const float bo1 = bo[j], bo2 = bo[256 + j], bo3 = bo[512 + j];
    const int h = j >> 5, d = j & 31;
    #pragma unroll
    for (int t = 0; t < TT; t++) {
        int m = m0 + t;
        int b = m >> 11, n = m & 2047;
        float dj = inv[t][j], nj = inv[t][HIDN + j];
        float o1 = a1[t] + bo1, o2 = a2[t] + bo2, o3 = a3[t] + bo3;
        float g = 1.f / (1.f + __expf(-(ag[t] + bgj)));
        size_t ob = (size_t)m * 1024;
        out[ob + j] = dj * o1 + nj * o2 + o3;
        size_t rbase = ((size_t)(b * NHEAD + h) * NSEQ + n) * 128;
        #pragma unroll
        for (int c = 0; c < 3; c++) {
            float va = oall[rbase + 32 + c * 32 + d];
            float vv = x[ob + (1 + c) * 256 + j];
            out[ob + (1 + c) * 256 + j] = g * va + vv;
        }
    }
}

// ---------------------------------------------------------------------------
extern "C" void kernel_launch(void* const* d_in, const int* in_sizes, int n_in,
                              void* d_out, int out_size, void* d_ws, size_t ws_size,
                              hipStream_t stream)
{
    const float* x    = (const float*)d_in[0];
    const float* Wq   = (const float*)d_in[1];
    const float* bq   = (const float*)d_in[2];
    const float* Wk   = (const float*)d_in[3];
    const float* bk   = (const float*)d_in[4];
    const float* Wv   = (const float*)d_in[5];
    const float* bv   = (const float*)d_in[6];
    const float* Wvec = (const float*)d_in[7];
    const float* Wo   = (const float*)d_in[8];
    const float* bo   = (const float*)d_in[9];
    const float* Wg   = (const float*)d_in[10];
    const float* bg   = (const float*)d_in[11];
    const float* adp  = (const float*)d_in[12];
    const float* anp  = (const float*)d_in[13];
    float* out = (float*)d_out;

    float* ws    = (float*)d_ws;
    short* qbf   = (short*)ws;                 // 2,097,152 bf16
    short* kbf   = (short*)(ws + 1048576);     // 2,097,152 bf16
    short* vtb   = (short*)(ws + 2097152);     // 8,388,608 bf16
    float* dotb  = ws + 6291456;               // 2,097,152 f32
    float* normb = ws + 8388608;               // 2,097,152 f32
    float* oallb = ws + 10485760;              // 8,388,608 f32
    short* Wqkvb = (short*)(ws + 18874368);    // 196,608 bf16
    float* bqkvs = ws + 18972672;              // 768 f32
    short* Wvecb = (short*)(ws + 18973440);    // 131,072 bf16
    // total ~76.2 MB

    wcvt_kernel<<<1280, 256, 0, stream>>>(Wq, Wk, Wv, Wvec, bq, bk, bv,
                                          Wqkvb, Wvecb, bqkvs);
    qkv_kernel<<<dim3(256, 3), 256, 0, stream>>>(x, Wqkvb, bqkvs, qbf, kbf, vtb);
    vdot_kernel<<<512, 512, 0, stream>>>(x, Wvecb, dotb);
    vecel_kernel<<<512, 256, 0, stream>>>(x, normb, vtb);
    attn_kernel<<<512, 256, 0, stream>>>(qbf, kbf, vtb, oallb);
    epi_kernel<<<512, 256, 0, stream>>>(x, dotb, normb, oallb,
                                        Wg, bg, Wo, bo, adp, anp, out);
}

// Round 4
// 335.087 us; speedup vs baseline: 7.6136x; 1.2384x over previous
//
#include <hip/hip_runtime.h>
#include <cstdint>
#include <cstddef>

#define HIDN 256
#define NHEAD 8
#define HD 32
#define NSEQ 2048
#define QS (0.17677669529663687f * 1.4426950408889634f)   // 1/sqrt(32) * log2(e)

typedef __attribute__((ext_vector_type(8))) short short8;
typedef __attribute__((ext_vector_type(4))) short short4v;
typedef __attribute__((ext_vector_type(4))) float f32x4;

static __device__ __forceinline__ short f2bf(float f) {
    union { float f; uint32_t u; } v; v.f = f;
    uint32_t r = (v.u + 0x7FFF + ((v.u >> 16) & 1)) >> 16;
    return (short)r;
}
static __device__ __forceinline__ float bf2f(short s) {
    union { uint32_t u; float f; } v; v.u = ((uint32_t)(uint16_t)s) << 16;
    return v.f;
}

// ---------------------------------------------------------------------------
// Kernel 0: weight conversion. Wq gets QS folded; Wg gets alpha_dot/alpha_norm
// folded into its columns. grid 2560 x 256 covers 655,360 elements.
// ---------------------------------------------------------------------------
__global__ __launch_bounds__(256) void wcvt_kernel(
    const float* __restrict__ Wq, const float* __restrict__ Wk,
    const float* __restrict__ Wv, const float* __restrict__ Wvec,
    const float* __restrict__ Wo, const float* __restrict__ Wg,
    const float* __restrict__ bq, const float* __restrict__ bk,
    const float* __restrict__ bv,
    const float* __restrict__ ad, const float* __restrict__ an,
    short* __restrict__ Wqkvb, short* __restrict__ Wvecb,
    short* __restrict__ Wob, short* __restrict__ Wgb, float* __restrict__ bqkvs)
{
    int idx = blockIdx.x * 256 + threadIdx.x;
    if (idx < 65536)        Wqkvb[idx] = f2bf(Wq[idx] * QS);
    else if (idx < 131072)  Wqkvb[idx] = f2bf(Wk[idx - 65536]);
    else if (idx < 196608)  Wqkvb[idx] = f2bf(Wv[idx - 131072]);
    else if (idx < 327680)  Wvecb[idx - 196608] = f2bf(Wvec[idx - 196608]);
    else if (idx < 524288)  Wob[idx - 327680] = f2bf(Wo[idx - 327680]);
    else {
        int i2 = idx - 524288;
        int k = i2 & 511;
        float s = (k < 256) ? ad[0] : an[0];
        Wgb[i2] = f2bf(Wg[i2] * s);
    }
    if (idx < 256)          bqkvs[idx] = bq[idx] * QS;
    else if (idx < 512)     bqkvs[idx] = bk[idx - 256];
    else if (idx < 768)     bqkvs[idx] = bv[idx - 512];
}

// ---------------------------------------------------------------------------
// Kernel 1: QKV via MFMA. grid (256 token-tiles of 32, 3: q/k/v). Block 256.
// ---------------------------------------------------------------------------
__global__ __launch_bounds__(256) void qkv_kernel(
    const float* __restrict__ x, const short* __restrict__ Wqkvb,
    const float* __restrict__ bqkvs,
    short* __restrict__ qbf, short* __restrict__ kbf, short* __restrict__ vtb)
{
    __shared__ short xs[32 * 264];
    __shared__ short vtmp[256 * 34];
    const int tid = threadIdx.x;
    const int m0 = blockIdx.x * 32;
    const int y  = blockIdx.y;
    const int b  = m0 >> 11;
    const int n0 = m0 & 2047;

    #pragma unroll
    for (int l = 0; l < 8; l++) {
        int i = l * 256 + tid;
        int t = i >> 6, j4 = i & 63;
        float4 v = *(const float4*)(x + (size_t)(m0 + t) * 1024 + j4 * 4);
        short4v s = { f2bf(v.x), f2bf(v.y), f2bf(v.z), f2bf(v.w) };
        *(short4v*)&xs[t * 264 + j4 * 4] = s;
    }
    __syncthreads();

    const int wave = tid >> 6, lane = tid & 63;
    const int col = lane & 15, quad = lane >> 4;

    f32x4 acc[2][4];
    #pragma unroll
    for (int mt = 0; mt < 2; mt++)
        #pragma unroll
        for (int nt = 0; nt < 4; nt++) acc[mt][nt] = (f32x4){0.f,0.f,0.f,0.f};

    const short* Wb = Wqkvb + (size_t)(y * 256 + wave * 64) * 256;
    #pragma unroll
    for (int kk = 0; kk < 8; kk++) {
        short8 xf[2];
        #pragma unroll
        for (int mt = 0; mt < 2; mt++)
            xf[mt] = *(const short8*)&xs[(mt * 16 + col) * 264 + kk * 32 + quad * 8];
        #pragma unroll
        for (int nt = 0; nt < 4; nt++) {
            short8 wf = *(const short8*)(Wb + (size_t)(nt * 16 + col) * 256 + kk * 32 + quad * 8);
            #pragma unroll
            for (int mt = 0; mt < 2; mt++)
                acc[mt][nt] = __builtin_amdgcn_mfma_f32_16x16x32_bf16(wf, xf[mt], acc[mt][nt], 0, 0, 0);
        }
    }

    if (y < 2) {
        short* dst = (y == 0) ? qbf : kbf;
        #pragma unroll
        for (int nt = 0; nt < 4; nt++) {
            int ch = wave * 64 + nt * 16 + quad * 4;
            float4 bi = *(const float4*)&bqkvs[y * 256 + ch];
            int h = ch >> 5, d = ch & 31;
            #pragma unroll
            for (int mt = 0; mt < 2; mt++) {
                int n = n0 + mt * 16 + col;
                short4v s = { f2bf(acc[mt][nt][0] + bi.x), f2bf(acc[mt][nt][1] + bi.y),
                              f2bf(acc[mt][nt][2] + bi.z), f2bf(acc[mt][nt][3] + bi.w) };
                *(short4v*)(dst + ((size_t)(b * 8 + h) * 2048 + n) * 32 + d) = s;
            }
        }
    } else {
        #pragma unroll
        for (int nt = 0; nt < 4; nt++) {
            int ch = wave * 64 + nt * 16 + quad * 4;
            float4 bi = *(const float4*)&bqkvs[512 + ch];
            #pragma unroll
            for (int mt = 0; mt < 2; mt++) {
                int tok = mt * 16 + col;
                vtmp[(ch + 0) * 34 + tok] = f2bf(acc[mt][nt][0] + bi.x);
                vtmp[(ch + 1) * 34 + tok] = f2bf(acc[mt][nt][1] + bi.y);
                vtmp[(ch + 2) * 34 + tok] = f2bf(acc[mt][nt][2] + bi.z);
                vtmp[(ch + 3) * 34 + tok] = f2bf(acc[mt][nt][3] + bi.w);
            }
        }
        __syncthreads();
        int ch = tid;
        short s[32];
        #pragma unroll
        for (int t = 0; t < 32; t++) s[t] = vtmp[ch * 34 + t];
        size_t row = ((size_t)(b * 8 + (ch >> 5)) * 128 + (ch & 31)) * 2048 + n0;
        #pragma unroll
        for (int g = 0; g < 4; g++)
            *(short8*)(vtb + row + g * 8) = *(short8*)&s[g * 8];
    }
}

// ---------------------------------------------------------------------------
// Kernel 2: vec_dot via MFMA; also writes bf16 inv[:,0:256].
// ---------------------------------------------------------------------------
__global__ __launch_bounds__(512) void vdot_kernel(
    const float* __restrict__ x, const short* __restrict__ Wvecb,
    float* __restrict__ dotb, short* __restrict__ invb)
{
    __shared__ short vb[3 * 16 * 264];
    const int tid = threadIdx.x;
    const int m0 = blockIdx.x * 16;

    #pragma unroll
    for (int p = 0; p < 6; p++) {
        int f4 = p * 512 + tid;
        int t = f4 / 192;
        int rem = f4 - t * 192;
        int c = rem >> 6, j4 = rem & 63;
        float4 v = *(const float4*)(x + (size_t)(m0 + t) * 1024 + 256 + c * 256 + j4 * 4);
        short4v s = { f2bf(v.x), f2bf(v.y), f2bf(v.z), f2bf(v.w) };
        *(short4v*)&vb[(c * 16 + t) * 264 + j4 * 4] = s;
    }
    __syncthreads();

    const int wave = tid >> 6, lane = tid & 63;
    const int col = lane & 15, quad = lane >> 4;
    const int j0 = wave * 32;

    f32x4 dac[2] = {(f32x4){0.f,0.f,0.f,0.f}, (f32x4){0.f,0.f,0.f,0.f}};
    #pragma unroll
    for (int c = 0; c < 3; c++) {
        f32x4 d1[2] = {(f32x4){0.f,0.f,0.f,0.f}, (f32x4){0.f,0.f,0.f,0.f}};
        f32x4 d2[2] = {(f32x4){0.f,0.f,0.f,0.f}, (f32x4){0.f,0.f,0.f,0.f}};
        #pragma unroll
        for (int kk = 0; kk < 8; kk++) {
            short8 xf = *(const short8*)&vb[(c * 16 + col) * 264 + kk * 32 + quad * 8];
            #pragma unroll
            for (int nt = 0; nt < 2; nt++) {
                short8 w1 = *(const short8*)&Wvecb[(size_t)(j0 + nt * 16 + col) * 256 + kk * 32 + quad * 8];
                short8 w2 = *(const short8*)&Wvecb[(size_t)(256 + j0 + nt * 16 + col) * 256 + kk * 32 + quad * 8];
                d1[nt] = __builtin_amdgcn_mfma_f32_16x16x32_bf16(w1, xf, d1[nt], 0, 0, 0);
                d2[nt] = __builtin_amdgcn_mfma_f32_16x16x32_bf16(w2, xf, d2[nt], 0, 0, 0);
            }
        }
        #pragma unroll
        for (int nt = 0; nt < 2; nt++) dac[nt] += d1[nt] * d2[nt];
    }
    #pragma unroll
    for (int nt = 0; nt < 2; nt++) {
        float4 o = { dac[nt][0], dac[nt][1], dac[nt][2], dac[nt][3] };
        *(float4*)&dotb[(size_t)(m0 + col) * 256 + j0 + nt * 16 + quad * 4] = o;
        short4v s = { f2bf(dac[nt][0]), f2bf(dac[nt][1]), f2bf(dac[nt][2]), f2bf(dac[nt][3]) };
        *(short4v*)&invb[(size_t)(m0 + col) * 512 + j0 + nt * 16 + quad * 4] = s;
    }
}

// ---------------------------------------------------------------------------
// Kernel 3: vec_norm (fp32 + bf16 inv[:,256:512]) + bf16 V^T rows 32..127.
// ---------------------------------------------------------------------------
__global__ __launch_bounds__(256) void vecel_kernel(
    const float* __restrict__ x, float* __restrict__ normb,
    short* __restrict__ invb, short* __restrict__ vtb)
{
    const int j = threadIdx.x;
    const int m0 = blockIdx.x * 16;
    const int b = m0 >> 11, n0 = m0 & 2047;
    const int h = j >> 5, d = j & 31;
    float vv[3][16];
    #pragma unroll
    for (int t = 0; t < 16; t++) {
        const float* xr = x + (size_t)(m0 + t) * 1024 + 256;
        float v0 = xr[j], v1 = xr[256 + j], v2 = xr[512 + j];
        vv[0][t] = v0; vv[1][t] = v1; vv[2][t] = v2;
        float nm = sqrtf(v0 * v0 + v1 * v1 + v2 * v2);
        normb[(size_t)(m0 + t) * 256 + j] = nm;
        invb[(size_t)(m0 + t) * 512 + 256 + j] = f2bf(nm);
    }
    #pragma unroll
    for (int c = 0; c < 3; c++) {
        short8 s0, s1;
        #pragma unroll
        for (int t = 0; t < 8; t++) { s0[t] = f2bf(vv[c][t]); s1[t] = f2bf(vv[c][8 + t]); }
        size_t row = ((size_t)(b * 8 + h) * 128 + 32 + c * 32 + d) * 2048 + n0;
        *(short8*)(vtb + row) = s0;
        *(short8*)(vtb + row + 8) = s1;
    }
}

// ---------------------------------------------------------------------------
// Kernel 4: MFMA flash attention. Writes bf16 x_out (m,256) and fp32
// vec_aggr (m,3,256) directly in epilogue layouts.
// ---------------------------------------------------------------------------
__global__ __launch_bounds__(256) void attn_kernel(
    const short* __restrict__ qb, const short* __restrict__ kb,
    const short* __restrict__ vtb,
    short* __restrict__ xob, float* __restrict__ ovb)
{
    __shared__ short Ks[64 * 36];
    __shared__ short Vs[128 * 68];
    __shared__ short Pl[4][2][16 * 72];
    const int tid = threadIdx.x;
    const int wave = tid >> 6, lane = tid & 63;
    const int col = lane & 15, quad = lane >> 4;
    const int bh = blockIdx.x >> 4, qt = blockIdx.x & 15;
    const int m0 = qt * 128 + wave * 32;
    const int b = bh >> 3, h = bh & 7;

    const short* qbase = qb + (size_t)bh * NSEQ * HD;
    const short* kbase = kb + (size_t)bh * NSEQ * HD;
    const short* vbase = vtb + (size_t)bh * 128 * NSEQ;

    short8 qfrag[2];
    #pragma unroll
    for (int s = 0; s < 2; s++)
        qfrag[s] = *(const short8*)(qbase + (size_t)(m0 + s * 16 + col) * 32 + quad * 8);

    f32x4 o[2][8];
    #pragma unroll
    for (int s = 0; s < 2; s++)
        #pragma unroll
        for (int dt = 0; dt < 8; dt++) o[s][dt] = (f32x4){0.f,0.f,0.f,0.f};
    float mrun[2] = {-1e30f, -1e30f};
    float lrun[2] = {0.f, 0.f};

    for (int kt = 0; kt < 32; kt++) {
        __syncthreads();
        {
            int r = tid >> 2, seg = tid & 3;
            *(short8*)&Ks[r * 36 + seg * 8] =
                *(const short8*)(kbase + (size_t)(kt * 64 + r) * 32 + seg * 8);
        }
        #pragma unroll
        for (int p = 0; p < 4; p++) {
            int i = p * 256 + tid;
            int r = i >> 3, seg = i & 7;
            *(short8*)&Vs[r * 68 + seg * 8] =
                *(const short8*)(vbase + (size_t)r * NSEQ + kt * 64 + seg * 8);
        }
        __syncthreads();

        short8 kf[4];
        #pragma unroll
        for (int nt = 0; nt < 4; nt++)
            kf[nt] = *(const short8*)&Ks[(nt * 16 + col) * 36 + quad * 8];

        float alpha[2];
        #pragma unroll
        for (int s = 0; s < 2; s++) {
            f32x4 sc[4];
            #pragma unroll
            for (int nt = 0; nt < 4; nt++)
                sc[nt] = __builtin_amdgcn_mfma_f32_16x16x32_bf16(
                    kf[nt], qfrag[s], (f32x4){0.f,0.f,0.f,0.f}, 0, 0, 0);
            float mx = -1e30f;
            #pragma unroll
            for (int nt = 0; nt < 4; nt++)
                #pragma unroll
                for (int r = 0; r < 4; r++) mx = fmaxf(mx, sc[nt][r]);
            mx = fmaxf(mx, __shfl_xor(mx, 16));
            mx = fmaxf(mx, __shfl_xor(mx, 32));
            float mnew = fmaxf(mrun[s], mx);
            alpha[s] = exp2f(mrun[s] - mnew);
            mrun[s] = mnew;
            float rs = 0.f;
            short* pd = &Pl[wave][s][col * 72];
            #pragma unroll
            for (int nt = 0; nt < 4; nt++) {
                short4v pk;
                #pragma unroll
                for (int r = 0; r < 4; r++) {
                    float p = exp2f(sc[nt][r] - mnew);
                    rs += p;
                    pk[r] = f2bf(p);
                }
                *(short4v*)(pd + nt * 16 + quad * 4) = pk;
            }
            rs += __shfl_xor(rs, 16);
            rs += __shfl_xor(rs, 32);
            lrun[s] = lrun[s] * alpha[s] + rs;
        }

        #pragma unroll
        for (int s = 0; s < 2; s++)
            #pragma unroll
            for (int dt = 0; dt < 8; dt++) o[s][dt] *= alpha[s];

        #pragma unroll
        for (int c = 0; c < 2; c++) {
            short8 pa[2];
            #pragma unroll
            for (int s = 0; s < 2; s++)
                pa[s] = *(const short8*)&Pl[wave][s][col * 72 + c * 32 + quad * 8];
            #pragma unroll
            for (int dt = 0; dt < 8; dt++) {
                short8 vf = *(const short8*)&Vs[(dt * 16 + col) * 68 + c * 32 + quad * 8];
                #pragma unroll
                for (int s = 0; s < 2; s++)
                    o[s][dt] = __builtin_amdgcn_mfma_f32_16x16x32_bf16(vf, pa[s], o[s][dt], 0, 0, 0);
            }
        }
    }

    #pragma unroll
    for (int s = 0; s < 2; s++) {
        float linv = 1.0f / lrun[s];
        size_t mg = (size_t)b * 2048 + m0 + s * 16 + col;
        short* xr = xob + mg * 256 + h * 32;
        #pragma unroll
        for (int dt = 0; dt < 2; dt++) {
            short4v sv = { f2bf(o[s][dt][0] * linv), f2bf(o[s][dt][1] * linv),
                           f2bf(o[s][dt][2] * linv), f2bf(o[s][dt][3] * linv) };
            *(short4v*)(xr + dt * 16 + quad * 4) = sv;
        }
        float* vr = ovb + mg * 768 + h * 32;
        #pragma unroll
        for (int dt = 2; dt < 8; dt++) {
            int c = (dt - 2) >> 1, d2 = ((dt - 2) & 1) * 16 + quad * 4;
            float4 f = { o[s][dt][0] * linv, o[s][dt][1] * linv,
                         o[s][dt][2] * linv, o[s][dt][3] * linv };
            *(float4*)(vr + c * 256 + d2) = f;
        }
    }
}

// ---------------------------------------------------------------------------
// Kernel 5: MFMA epilogue GEMM + fused combine. grid 512 (m-tiles of 16),
// block 256: wave0 = gate (K=512), waves1-3 = o1/o2/o3 (K=256).
// ---------------------------------------------------------------------------
__global__ __launch_bounds__(256) void ogemm_kernel(
    const float* __restrict__ x, const short* __restrict__ xob,
    const short* __restrict__ invb,
    const float* __restrict__ dotb, const float* __restrict__ normb,
    const float* __restrict__ ovb,
    const short* __restrict__ Wob, const short* __restrict__ Wgb,
    const float* __restrict__ bo, const float* __restrict__ bg,
    float* __restrict__ out)
{
    __shared__ __align__(16) union {
        struct { short inv[16 * 520]; short xo[16 * 264]; } in;   // 25.1 KB
        struct { short gate[16 * 264]; short o[16 * 776]; } ob;   // 32.5 KB
    } u;
    const int tid = threadIdx.x;
    const int M0 = blockIdx.x * 16;

    #pragma unroll
    for (int l = 0; l < 4; l++) {
        int i = l * 256 + tid;
        int m = i >> 6, seg = i & 63;
        *(short8*)&u.in.inv[m * 520 + seg * 8] =
            *(const short8*)(invb + (size_t)(M0 + m) * 512 + seg * 8);
    }
    #pragma unroll
    for (int l = 0; l < 2; l++) {
        int i = l * 256 + tid;
        int m = i >> 5, seg = i & 31;
        *(short8*)&u.in.xo[m * 264 + seg * 8] =
            *(const short8*)(xob + (size_t)(M0 + m) * 256 + seg * 8);
    }
    __syncthreads();

    const int wave = tid >> 6, lane = tid & 63;
    const int col = lane & 15, quad = lane >> 4;

    f32x4 acc[16];
    #pragma unroll
    for (int nt = 0; nt < 16; nt++) acc[nt] = (f32x4){0.f,0.f,0.f,0.f};

    if (wave == 0) {
        #pragma unroll
        for (int kk = 0; kk < 16; kk++) {
            short8 xf = *(const short8*)&u.in.inv[col * 520 + kk * 32 + quad * 8];
            #pragma unroll
            for (int nt = 0; nt < 16; nt++) {
                short8 wf = *(const short8*)(Wgb + (size_t)(nt * 16 + col) * 512 + kk * 32 + quad * 8);
                acc[nt] = __builtin_amdgcn_mfma_f32_16x16x32_bf16(wf, xf, acc[nt], 0, 0, 0);
            }
        }
    } else {
        const short* Wb = Wob + (size_t)(wave - 1) * 256 * 256;
        #pragma unroll
        for (int kk = 0; kk < 8; kk++) {
            short8 xf = *(const short8*)&u.in.xo[col * 264 + kk * 32 + quad * 8];
            #pragma unroll
            for (int nt = 0; nt < 16; nt++) {
                short8 wf = *(const short8*)(Wb + (size_t)(nt * 16 + col) * 256 + kk * 32 + quad * 8);
                acc[nt] = __builtin_amdgcn_mfma_f32_16x16x32_bf16(wf, xf, acc[nt], 0, 0, 0);
            }
        }
    }
    __syncthreads();

    if (wave == 0) {
        #pragma unroll
        for (int nt = 0; nt < 16; nt++) {
            int ch = nt * 16 + quad * 4;
            float4 bi = *(const float4*)&bg[ch];
            short4v s = { f2bf(1.f / (1.f + __expf(-(acc[nt][0] + bi.x)))),
                          f2bf(1.f / (1.f + __expf(-(acc[nt][1] + bi.y)))),
                          f2bf(1.f / (1.f + __expf(-(acc[nt][2] + bi.z)))),
                          f2bf(1.f / (1.f + __expf(-(acc[nt][3] + bi.w)))) };
            *(short4v*)&u.ob.gate[col * 264 + ch] = s;
        }
    } else {
        #pragma unroll
        for (int nt = 0; nt < 16; nt++) {
            int ch = (wave - 1) * 256 + nt * 16 + quad * 4;
            float4 bi = *(const float4*)&bo[ch];
            short4v s = { f2bf(acc[nt][0] + bi.x), f2bf(acc[nt][1] + bi.y),
                          f2bf(acc[nt][2] + bi.z), f2bf(acc[nt][3] + bi.w) };
            *(short4v*)&u.ob.o[col * 776 + ch] = s;
        }
    }
    __syncthreads();

    // fused combine: 16 tokens x 1024 floats, float4-vectorized, coalesced
    #pragma unroll
    for (int l = 0; l < 16; l++) {
        int idx4 = l * 256 + tid;
        int m = idx4 >> 8;
        int j = (idx4 & 255) * 4;
        size_t mg = (size_t)(M0 + m);
        if (j < 256) {
            float4 dv = *(const float4*)(dotb + mg * 256 + j);
            float4 nv = *(const float4*)(normb + mg * 256 + j);
            short4v o1 = *(short4v*)&u.ob.o[m * 776 + j];
            short4v o2 = *(short4v*)&u.ob.o[m * 776 + 256 + j];
            short4v o3 = *(short4v*)&u.ob.o[m * 776 + 512 + j];
            float4 r;
            r.x = dv.x * bf2f(o1[0]) + nv.x * bf2f(o2[0]) + bf2f(o3[0]);
            r.y = dv.y * bf2f(o1[1]) + nv.y * bf2f(o2[1]) + bf2f(o3[1]);
            r.z = dv.z * bf2f(o1[2]) + nv.z * bf2f(o2[2]) + bf2f(o3[2]);
            r.w = dv.w * bf2f(o1[3]) + nv.w * bf2f(o2[3]) + bf2f(o3[3]);
            *(float4*)(out + mg * 1024 + j) = r;
        } else {
            int c = (j >> 8) - 1, jj = j & 255;
            short4v g4 = *(short4v*)&u.ob.gate[m * 264 + jj];
            float4 av = *(const float4*)(ovb + mg * 768 + c * 256 + jj);
            float4 xv = *(const float4*)(x + mg * 1024 + 256 + c * 256 + jj);
            float4 r = { bf2f(g4[0]) * av.x + xv.x, bf2f(g4[1]) * av.y + xv.y,
                         bf2f(g4[2]) * av.z + xv.z, bf2f(g4[3]) * av.w + xv.w };
            *(float4*)(out + mg * 1024 + j) = r;
        }
    }
}

// ---------------------------------------------------------------------------
extern "C" void kernel_launch(void* const* d_in, const int* in_sizes, int n_in,
                              void* d_out, int out_size, void* d_ws, size_t ws_size,
                              hipStream_t stream)
{
    const float* x    = (const float*)d_in[0];
    const float* Wq   = (const float*)d_in[1];
    const float* bq   = (const float*)d_in[2];
    const float* Wk   = (const float*)d_in[3];
    const float* bk   = (const float*)d_in[4];
    const float* Wv   = (const float*)d_in[5];
    const float* bv   = (const float*)d_in[6];
    const float* Wvec = (const float*)d_in[7];
    const float* Wo   = (const float*)d_in[8];
    const float* bo   = (const float*)d_in[9];
    const float* Wg   = (const float*)d_in[10];
    const float* bg   = (const float*)d_in[11];
    const float* adp  = (const float*)d_in[12];
    const float* anp  = (const float*)d_in[13];
    float* out = (float*)d_out;

    float* ws    = (float*)d_ws;
    short* qbf   = (short*)ws;                 // 2,097,152 bf16 -> 1,048,576 f
    short* kbf   = (short*)(ws + 1048576);     // 1,048,576 f
    short* vtb   = (short*)(ws + 2097152);     // 4,194,304 f
    float* dotb  = ws + 6291456;               // 2,097,152 f
    float* normb = ws + 8388608;               // 2,097,152 f
    short* xob   = (short*)(ws + 10485760);    // 1,048,576 f
    float* ovb   = ws + 11534336;              // 6,291,456 f
    short* invb  = (short*)(ws + 17825792);    // 2,097,152 f
    short* Wqkvb = (short*)(ws + 19922944);    // 98,304 f
    float* bqkvs = ws + 20021248;              // 768 f
    short* Wvecb = (short*)(ws + 20022016);    // 65,536 f
    short* Wob   = (short*)(ws + 20087552);    // 98,304 f
    short* Wgb   = (short*)(ws + 20185856);    // 65,536 f
    // total ~81 MB

    wcvt_kernel<<<2560, 256, 0, stream>>>(Wq, Wk, Wv, Wvec, Wo, Wg, bq, bk, bv,
                                          adp, anp, Wqkvb, Wvecb, Wob, Wgb, bqkvs);
    qkv_kernel<<<dim3(256, 3), 256, 0, stream>>>(x, Wqkvb, bqkvs, qbf, kbf, vtb);
    vdot_kernel<<<512, 512, 0, stream>>>(x, Wvecb, dotb, invb);
    vecel_kernel<<<512, 256, 0, stream>>>(x, normb, invb, vtb);
    attn_kernel<<<512, 256, 0, stream>>>(qbf, kbf, vtb, xob, ovb);
    ogemm_kernel<<<512, 256, 0, stream>>>(x, xob, invb, dotb, normb, ovb,
                                          Wob, Wgb, bo, bg, out);
}